// Round 7
// baseline (47.158 us; speedup 1.0000x reference)
//
#include <hip/hip_runtime.h>

#define NB 16
#define NN 256
#define NH 128
#define NE 16

typedef float v4f  __attribute__((ext_vector_type(4)));
typedef short bf16x8 __attribute__((ext_vector_type(8)));
typedef unsigned int uint;

constexpr long long EF_ELEMS = (long long)NB * NN * NN * NE; // 16777216

// ws layout (floats): bps[16] | albe[1280] | Pi[4096*32] | Pj[4096*32]

// ==================== A: fused prep (block 1024) + proj (blocks 0..1023) ============
__global__ __launch_bounds__(256) void k_prep_proj(
    const float* __restrict__ node, const float* __restrict__ uW1,
    const float* __restrict__ dW1, const float* __restrict__ db1,
    const float* __restrict__ dW2, const float* __restrict__ db2,
    const float* __restrict__ ub1,
    float* __restrict__ bps, float* __restrict__ albe,
    float* __restrict__ Pi, float* __restrict__ Pj)
{
    const int t = threadIdx.x;
    if (blockIdx.x == 1024) {
        __shared__ float sM[512];      // M[16][32] = dW2 @ uW1[256:,:]
        __shared__ float sBp[16];
        __shared__ float sA[16], sB[16];
        for (int i = t; i < 512; i += 256) {
            const int k = i >> 5, c = i & 31;
            float s = 0.f;
#pragma unroll
            for (int e = 0; e < 16; ++e)
                s = fmaf(dW2[k * 16 + e], uW1[(256 + e) * 32 + c], s);
            sM[i] = s;
        }
        if (t < 16) { sA[t] = dW1[t]; sB[t] = db1[t]; }
        __syncthreads();
        if (t < 16) {
            const float a = sA[t];
            const float x = (a != 0.f) ? (-sB[t] / a) : -1e30f;
            int r = 0;
            for (int q = 0; q < 16; ++q) {
                const float aq = sA[q];
                const float xq = (aq != 0.f) ? (-sB[q] / aq) : -1e30f;
                r += (xq < x) || (xq == x && q < t);
            }
            sBp[r] = x;
        }
        __syncthreads();
        if (t < 16) bps[t] = sBp[t];
        for (int i = t; i < 544; i += 256) {
            const int s = i >> 5, c = i & 31;
            float dt;
            if (s == 0)       dt = sBp[0] - 1.0f;
            else if (s == 16) dt = sBp[15] + 1.0f;
            else              dt = 0.5f * (sBp[s - 1] + sBp[s]);
            float alpha = 0.f, beta = 0.f;
#pragma unroll
            for (int k = 0; k < 16; ++k) {
                if (fmaf(sA[k], dt, sB[k]) > 0.f) {
                    const float m = sM[k * 32 + c];
                    alpha = fmaf(sA[k], m, alpha);
                    beta  = fmaf(sB[k], m, beta);
                }
            }
            float c2 = ub1[c];
#pragma unroll
            for (int e = 0; e < 16; ++e)
                c2 = fmaf(db2[e], uW1[(256 + e) * 32 + c], c2);
            albe[s * 68 + c]      = alpha;
            albe[s * 68 + 32 + c] = beta + c2;
        }
        for (int i = 1156 + t; i < 1280; i += 256) albe[i] = 0.f;  // pad for vec copy
    } else {
        const int r = t >> 6, sub = t & 63;
        const int row = blockIdx.x * 4 + r;
        __shared__ float nrow[4][128];
        nrow[r][sub]      = node[(size_t)row * 128 + sub];
        nrow[r][sub + 64] = node[(size_t)row * 128 + 64 + sub];
        __syncthreads();
        const int c = sub & 31;
        const int half = sub >> 5;        // 0 -> Pi, 1 -> Pj
        const float* w = uW1 + half * 128 * 32 + c;
        float s = 0.f;
#pragma unroll 8
        for (int k = 0; k < 128; ++k)
            s = fmaf(nrow[r][k], w[k * 32], s);
        (half ? Pj : Pi)[(size_t)row * 32 + c] = s;
    }
}

// ==================== B: edge (2 rows/block, MFMA epilogue) + node MLP ===============
__global__ __launch_bounds__(256, 6) void k_edge5(
    const float* __restrict__ dist, const int* __restrict__ visited,
    const float* __restrict__ ln_g, const float* __restrict__ ln_b,
    const float* __restrict__ uW2, const float* __restrict__ ub2,
    const float* __restrict__ bps, const float* __restrict__ albe_g,
    const float* __restrict__ Pi, const float* __restrict__ Pj,
    const float* __restrict__ nW1, const float* __restrict__ nb1,
    const float* __restrict__ nW2, const float* __restrict__ nb2,
    float* __restrict__ ef_out, float* __restrict__ msg_out)
{
    const int row0 = blockIdx.x * 2;      // 2 rows, same batch b
    const int b = row0 >> 8;
    const int j = threadIdx.x;

    __shared__ float albe_s[1280];        // 5120 B
    __shared__ uint  h_lds[256 * 18];     // 18432 B, stride 18 -> conflict-free reads
    __shared__ float red2[2][4][16];      // 512 B
    __shared__ float pool_s[2][16];       // 128 B
    __shared__ float hid_s[2][64];        // 512 B
    // total ~24.7 KB -> 6 blocks/CU

    // stage albe (320 float4)
    {
        const float4* ag = reinterpret_cast<const float4*>(albe_g);
        float4* as = reinterpret_cast<float4*>(albe_s);
        for (int q = j; q < 320; q += 256) as[q] = ag[q];
    }

    const int lane = j & 63, wv = j >> 6;
    const int eRow = lane & 15;           // A row (e) / B col (edge-in-tile)
    const int g    = lane >> 4;           // k-group

    // Build A-fragments (uW2^T, bf16 hi/lo split) directly in registers.
    // Lane needs channels c = 2q, 2q+1 for q = g*4+p, p=0..3; same cvt_pk order as
    // the verified LDS-staged version, so the MFMA K-pairing is unchanged.
    bf16x8 ahi, alo;
    {
        union { uint u[4]; bf16x8 v; } Uhi, Ulo;
#pragma unroll
        for (int p = 0; p < 4; ++p) {
            const int q = g * 4 + p;
            const float w0 = uW2[(2 * q) * 16 + eRow];
            const float w1 = uW2[(2 * q + 1) * 16 + eRow];
            uint W00, W11, Whi, Wlo;
            asm("v_cvt_pk_bf16_f32 %0, %1, %2" : "=v"(W00) : "v"(w0), "v"(w0));
            asm("v_cvt_pk_bf16_f32 %0, %1, %2" : "=v"(W11) : "v"(w1), "v"(w1));
            const float w0h = __uint_as_float(W00 << 16);
            const float w1h = __uint_as_float(W11 << 16);
            asm("v_cvt_pk_bf16_f32 %0, %1, %2" : "=v"(Whi) : "v"(w0), "v"(w1));
            asm("v_cvt_pk_bf16_f32 %0, %1, %2" : "=v"(Wlo) : "v"(w0 - w0h), "v"(w1 - w1h));
            Uhi.u[p] = Whi;
            Ulo.u[p] = Wlo;
        }
        ahi = Uhi.v;
        alo = Ulo.v;
    }

    // preload dists
    float dq[2];
#pragma unroll
    for (int r = 0; r < 2; ++r)
        dq[r] = dist[(size_t)(row0 + r) * NN + j];

    const float4 ub2v = *reinterpret_cast<const float4*>(&ub2[g * 4]);
    const float4* pj4 = reinterpret_cast<const float4*>(Pj + ((size_t)(b * NN + j)) * 32);

    __syncthreads();   // albe_s ready

#pragma unroll
    for (int r = 0; r < 2; ++r) {
        const int row = row0 + r;
        const float d = dq[r];

        // segment lookup
        int seg = 0;
#pragma unroll
        for (int k = 0; k < 16; ++k) seg += (d > bps[k]) ? 1 : 0;
        const float* ab = &albe_s[seg * 68];

        // pre[c] = Pi[row][c] + Pj[b,j][c] + d*alpha[c] + beta[c]
        const float* PiRow = Pi + (size_t)row * 32;   // uniform -> s_load
        float pre[32];
#pragma unroll
        for (int q = 0; q < 8; ++q) {
            const float4 pv = pj4[q];                 // L1/L2-hit on r>0
            const float4 al = *reinterpret_cast<const float4*>(&ab[q * 4]);
            const float4 be = *reinterpret_cast<const float4*>(&ab[32 + q * 4]);
            pre[q * 4 + 0] = PiRow[q * 4 + 0] + pv.x + fmaf(d, al.x, be.x);
            pre[q * 4 + 1] = PiRow[q * 4 + 1] + pv.y + fmaf(d, al.y, be.y);
            pre[q * 4 + 2] = PiRow[q * 4 + 2] + pv.z + fmaf(d, al.z, be.z);
            pre[q * 4 + 3] = PiRow[q * 4 + 3] + pv.w + fmaf(d, al.w, be.w);
        }

        // LayerNorm over 32 channels
        float s0 = 0.f, s1 = 0.f, s2 = 0.f, s3 = 0.f;
#pragma unroll
        for (int c = 0; c < 32; c += 4) { s0 += pre[c]; s1 += pre[c+1]; s2 += pre[c+2]; s3 += pre[c+3]; }
        const float mu = ((s0 + s1) + (s2 + s3)) * (1.f / 32.f);
        float v0 = 0.f, v1 = 0.f, v2 = 0.f, v3 = 0.f;
#pragma unroll
        for (int c = 0; c < 32; c += 4) {
            pre[c]   -= mu; v0 = fmaf(pre[c],   pre[c],   v0);
            pre[c+1] -= mu; v1 = fmaf(pre[c+1], pre[c+1], v1);
            pre[c+2] -= mu; v2 = fmaf(pre[c+2], pre[c+2], v2);
            pre[c+3] -= mu; v3 = fmaf(pre[c+3], pre[c+3], v3);
        }
        const float rstd = rsqrtf(fmaf((v0 + v1) + (v2 + v3), 1.f / 32.f, 1e-5f));

        // h = relu(LN affine); pack to bf16 pairs -> LDS row j
#pragma unroll
        for (int c = 0; c < 32; ++c)
            pre[c] = fmaxf(fmaf(pre[c] * rstd, ln_g[c], ln_b[c]), 0.f);
        {
            uint hw[16];
#pragma unroll
            for (int q = 0; q < 16; ++q) {
                uint rr;
                asm("v_cvt_pk_bf16_f32 %0, %1, %2" : "=v"(rr) : "v"(pre[2*q]), "v"(pre[2*q+1]));
                hw[q] = rr;
            }
            uint* hrow = &h_lds[j * 18];
            *reinterpret_cast<uint4*>(hrow + 0)  = make_uint4(hw[0],  hw[1],  hw[2],  hw[3]);
            *reinterpret_cast<uint4*>(hrow + 4)  = make_uint4(hw[4],  hw[5],  hw[6],  hw[7]);
            *reinterpret_cast<uint4*>(hrow + 8)  = make_uint4(hw[8],  hw[9],  hw[10], hw[11]);
            *reinterpret_cast<uint4*>(hrow + 12) = make_uint4(hw[12], hw[13], hw[14], hw[15]);
        }
        // h_lds is wave-private (each wave reads only its own 64 rows); same-wave
        // DS program order makes write->read safe without a barrier.

        const float scale = visited[row] ? 0.5f : 1.0f;   // uniform
        v4f accsum = {0.f, 0.f, 0.f, 0.f};
#pragma unroll
        for (int t = 0; t < 4; ++t) {
            const int edge = wv * 64 + t * 16 + eRow;
            const bf16x8 bfr = *reinterpret_cast<const bf16x8*>(&h_lds[edge * 18 + g * 4]);
            v4f acc = {ub2v.x, ub2v.y, ub2v.z, ub2v.w};
            acc = __builtin_amdgcn_mfma_f32_16x16x32_bf16(alo, bfr, acc, 0, 0, 0);
            acc = __builtin_amdgcn_mfma_f32_16x16x32_bf16(ahi, bfr, acc, 0, 0, 0);
            acc[0] *= scale; acc[1] *= scale; acc[2] *= scale; acc[3] *= scale;
            *reinterpret_cast<v4f*>(ef_out + ((size_t)row * NN + edge) * 16 + g * 4) = acc;
            accsum += acc;
        }
#pragma unroll
        for (int rr = 0; rr < 4; ++rr) {
            float v = accsum[rr];
            v += __shfl_xor(v, 1);
            v += __shfl_xor(v, 2);
            v += __shfl_xor(v, 4);
            v += __shfl_xor(v, 8);
            accsum[rr] = v;
        }
        if (eRow == 0)
            *reinterpret_cast<v4f*>(&red2[r][wv][g * 4]) = accsum;
    }

    __syncthreads();   // red2 complete for both rows

    // pooled means (2 rows x 16 e = 32 threads)
    if (j < 32) {
        const int r = j >> 4, e = j & 15;
        pool_s[r][e] = (red2[r][0][e] + red2[r][1][e] + red2[r][2][e] + red2[r][3][e])
                       * (1.f / 256.f);
    }
    __syncthreads();

    // node MLP layer 1: hid[r][u] = relu(pool[r] @ nW1 + nb1)  (128 of 256 threads)
    if (j < 128) {
        const int r = j >> 6, u = j & 63;
        float s = nb1[u];
#pragma unroll
        for (int e = 0; e < 16; ++e)
            s = fmaf(pool_s[r][e], nW1[e * 64 + u], s);
        hid_s[r][u] = fmaxf(s, 0.f);
    }
    __syncthreads();

    // node MLP layer 2: msg[r][o] = hid[r] @ nW2 + nb2  (2x128 = 256 outputs, 1 pass)
    {
        const int r = j >> 7, o = j & 127;
        float s = nb2[o];
#pragma unroll 8
        for (int q = 0; q < 64; ++q)
            s = fmaf(hid_s[r][q], nW2[q * 128 + o], s);
        msg_out[(size_t)(row0 + r) * 128 + o] = s;
    }
}

extern "C" void kernel_launch(void* const* d_in, const int* in_sizes, int n_in,
                              void* d_out, int out_size, void* d_ws, size_t ws_size,
                              hipStream_t stream)
{
    const float* node    = (const float*)d_in[0];
    const float* dist    = (const float*)d_in[1];
    const int*   visited = (const int*)  d_in[2];
    const float* dW1     = (const float*)d_in[3];
    const float* db1     = (const float*)d_in[4];
    const float* dW2     = (const float*)d_in[5];
    const float* db2     = (const float*)d_in[6];
    const float* uW1     = (const float*)d_in[7];
    const float* ub1     = (const float*)d_in[8];
    const float* ln_g    = (const float*)d_in[9];
    const float* ln_b    = (const float*)d_in[10];
    const float* uW2     = (const float*)d_in[11];
    const float* ub2     = (const float*)d_in[12];
    const float* nW1     = (const float*)d_in[13];
    const float* nb1     = (const float*)d_in[14];
    const float* nW2     = (const float*)d_in[15];
    const float* nb2     = (const float*)d_in[16];

    float* ws   = (float*)d_ws;
    float* bps  = ws;                    // 16
    float* albe = ws + 16;               // 1280 (1156 used + pad)
    float* Pi   = ws + 16 + 1280;        // 4096*32
    float* Pj   = Pi + 4096 * 32;        // 4096*32

    float* out = (float*)d_out;
    float* msg = out + EF_ELEMS;

    hipLaunchKernelGGL(k_prep_proj, dim3(1025), dim3(256), 0, stream,
                       node, uW1, dW1, db1, dW2, db2, ub1, bps, albe, Pi, Pj);
    hipLaunchKernelGGL(k_edge5, dim3(2048), dim3(256), 0, stream,
                       dist, visited, ln_g, ln_b, uW2, ub2, bps, albe, Pi, Pj,
                       nW1, nb1, nW2, nb2, out, msg);
}

// Round 8
// 41.529 us; speedup vs baseline: 1.1355x; 1.1355x over previous
//
#include <hip/hip_runtime.h>

#define NB 16
#define NN 256
#define NH 128
#define NE 16

typedef float v4f  __attribute__((ext_vector_type(4)));
typedef short bf16x8 __attribute__((ext_vector_type(8)));
typedef unsigned int uint;

constexpr long long EF_ELEMS = (long long)NB * NN * NN * NE; // 16777216

// ws layout (floats): bps[16] | albe[1280] | Pi[4096*32] | Pj[4096*32]

// ==================== A: fused prep (block 1024) + proj (blocks 0..1023) ============
__global__ __launch_bounds__(256) void k_prep_proj(
    const float* __restrict__ node, const float* __restrict__ uW1,
    const float* __restrict__ dW1, const float* __restrict__ db1,
    const float* __restrict__ dW2, const float* __restrict__ db2,
    const float* __restrict__ ub1,
    float* __restrict__ bps, float* __restrict__ albe,
    float* __restrict__ Pi, float* __restrict__ Pj)
{
    const int t = threadIdx.x;
    if (blockIdx.x == 1024) {
        __shared__ float sM[512];      // M[16][32] = dW2 @ uW1[256:,:]
        __shared__ float sBp[16];
        __shared__ float sA[16], sB[16];
        for (int i = t; i < 512; i += 256) {
            const int k = i >> 5, c = i & 31;
            float s = 0.f;
#pragma unroll
            for (int e = 0; e < 16; ++e)
                s = fmaf(dW2[k * 16 + e], uW1[(256 + e) * 32 + c], s);
            sM[i] = s;
        }
        if (t < 16) { sA[t] = dW1[t]; sB[t] = db1[t]; }
        __syncthreads();
        if (t < 16) {
            const float a = sA[t];
            const float x = (a != 0.f) ? (-sB[t] / a) : -1e30f;
            int r = 0;
            for (int q = 0; q < 16; ++q) {
                const float aq = sA[q];
                const float xq = (aq != 0.f) ? (-sB[q] / aq) : -1e30f;
                r += (xq < x) || (xq == x && q < t);
            }
            sBp[r] = x;
        }
        __syncthreads();
        if (t < 16) bps[t] = sBp[t];
        for (int i = t; i < 544; i += 256) {
            const int s = i >> 5, c = i & 31;
            float dt;
            if (s == 0)       dt = sBp[0] - 1.0f;
            else if (s == 16) dt = sBp[15] + 1.0f;
            else              dt = 0.5f * (sBp[s - 1] + sBp[s]);
            float alpha = 0.f, beta = 0.f;
#pragma unroll
            for (int k = 0; k < 16; ++k) {
                if (fmaf(sA[k], dt, sB[k]) > 0.f) {
                    const float m = sM[k * 32 + c];
                    alpha = fmaf(sA[k], m, alpha);
                    beta  = fmaf(sB[k], m, beta);
                }
            }
            float c2 = ub1[c];
#pragma unroll
            for (int e = 0; e < 16; ++e)
                c2 = fmaf(db2[e], uW1[(256 + e) * 32 + c], c2);
            albe[s * 68 + c]      = alpha;
            albe[s * 68 + 32 + c] = beta + c2;
        }
        for (int i = 1156 + t; i < 1280; i += 256) albe[i] = 0.f;  // pad for vec copy
    } else {
        const int r = t >> 6, sub = t & 63;
        const int row = blockIdx.x * 4 + r;
        __shared__ float nrow[4][128];
        nrow[r][sub]      = node[(size_t)row * 128 + sub];
        nrow[r][sub + 64] = node[(size_t)row * 128 + 64 + sub];
        __syncthreads();
        const int c = sub & 31;
        const int half = sub >> 5;        // 0 -> Pi, 1 -> Pj
        const float* w = uW1 + half * 128 * 32 + c;
        float s = 0.f;
#pragma unroll 8
        for (int k = 0; k < 128; ++k)
            s = fmaf(nrow[r][k], w[k * 32], s);
        (half ? Pj : Pi)[(size_t)row * 32 + c] = s;
    }
}

// ==================== B: edge, 4 rows/block, software-pipelined =======================
// Per wave: write_h(0); for r: { compute_h(r+1) | mfma+store(r) | write_h(r+1) }.
// h_lds is wave-private and DS ops are in-order per wave, so a SINGLE h buffer is
// safe: mfma's ds_reads(r) precede write_h(r+1) in program order, and the
// compute_h(r+1) VALU block (~200 instrs) sits between write_h(r) and the reads.
__global__ __launch_bounds__(256, 4) void k_edge6(
    const float* __restrict__ dist, const int* __restrict__ visited,
    const float* __restrict__ ln_g, const float* __restrict__ ln_b,
    const float* __restrict__ uW2, const float* __restrict__ ub2,
    const float* __restrict__ bps, const float* __restrict__ albe_g,
    const float* __restrict__ Pi, const float* __restrict__ Pj,
    const float* __restrict__ nW1, const float* __restrict__ nb1,
    const float* __restrict__ nW2, const float* __restrict__ nb2,
    float* __restrict__ ef_out, float* __restrict__ msg_out)
{
    const int row0 = blockIdx.x * 4;      // 4 rows, same batch b
    const int b = row0 >> 8;
    const int j = threadIdx.x;

    __shared__ float albe_s[1280];        // 5120 B
    __shared__ uint  h_lds[256 * 17];     // 17408 B, stride 17: conflict-free r/w
    __shared__ float red2[4][4][16];      // 1024 B
    __shared__ float pool_s[4][16];       // 256 B
    __shared__ float hid_s[4][64];        // 1024 B
    // total ~24.8 KB

    // stage albe (320 float4)
    {
        const float4* ag = reinterpret_cast<const float4*>(albe_g);
        float4* as = reinterpret_cast<float4*>(albe_s);
        for (int q = j; q < 320; q += 256) as[q] = ag[q];
    }

    const int lane = j & 63, wv = j >> 6;
    const int eRow = lane & 15;           // A row (e) / B col (edge-in-tile)
    const int g    = lane >> 4;           // k-group

    // A-fragments (uW2^T, bf16 hi/lo split) in registers; same cvt_pk order as the
    // verified layout, so MFMA K-pairing is unchanged. Amortized over 4 rows.
    bf16x8 ahi, alo;
    {
        union { uint u[4]; bf16x8 v; } Uhi, Ulo;
#pragma unroll
        for (int p = 0; p < 4; ++p) {
            const int q = g * 4 + p;
            const float w0 = uW2[(2 * q) * 16 + eRow];
            const float w1 = uW2[(2 * q + 1) * 16 + eRow];
            uint W00, W11, Whi, Wlo;
            asm("v_cvt_pk_bf16_f32 %0, %1, %2" : "=v"(W00) : "v"(w0), "v"(w0));
            asm("v_cvt_pk_bf16_f32 %0, %1, %2" : "=v"(W11) : "v"(w1), "v"(w1));
            const float w0h = __uint_as_float(W00 << 16);
            const float w1h = __uint_as_float(W11 << 16);
            asm("v_cvt_pk_bf16_f32 %0, %1, %2" : "=v"(Whi) : "v"(w0), "v"(w1));
            asm("v_cvt_pk_bf16_f32 %0, %1, %2" : "=v"(Wlo) : "v"(w0 - w0h), "v"(w1 - w1h));
            Uhi.u[p] = Whi;
            Ulo.u[p] = Wlo;
        }
        ahi = Uhi.v;
        alo = Ulo.v;
    }

    // preload dists (coalesced per row)
    float dq[4];
#pragma unroll
    for (int r = 0; r < 4; ++r)
        dq[r] = dist[(size_t)(row0 + r) * NN + j];

    const float4 ub2v = *reinterpret_cast<const float4*>(&ub2[g * 4]);
    const float4* pj4 = reinterpret_cast<const float4*>(Pj + ((size_t)(b * NN + j)) * 32);
    float4 pj[8];
#pragma unroll
    for (int q = 0; q < 8; ++q) pj[q] = pj4[q];

    __syncthreads();   // albe_s ready (only block-wide barrier before the tail)

    // ---- pipeline helpers ------------------------------------------------------
    uint hw[16];
    auto compute_h = [&](int r) {
        const float d = dq[r];
        int seg = 0;
#pragma unroll
        for (int k = 0; k < 16; ++k) seg += (d > bps[k]) ? 1 : 0;
        const float* ab = &albe_s[seg * 68];
        const float* PiRow = Pi + (size_t)(row0 + r) * 32;   // uniform -> s_load
        float pre[32];
#pragma unroll
        for (int q = 0; q < 8; ++q) {
            const float4 al = *reinterpret_cast<const float4*>(&ab[q * 4]);
            const float4 be = *reinterpret_cast<const float4*>(&ab[32 + q * 4]);
            pre[q * 4 + 0] = PiRow[q * 4 + 0] + pj[q].x + fmaf(d, al.x, be.x);
            pre[q * 4 + 1] = PiRow[q * 4 + 1] + pj[q].y + fmaf(d, al.y, be.y);
            pre[q * 4 + 2] = PiRow[q * 4 + 2] + pj[q].z + fmaf(d, al.z, be.z);
            pre[q * 4 + 3] = PiRow[q * 4 + 3] + pj[q].w + fmaf(d, al.w, be.w);
        }
        float s0 = 0.f, s1 = 0.f, s2 = 0.f, s3 = 0.f;
#pragma unroll
        for (int c = 0; c < 32; c += 4) { s0 += pre[c]; s1 += pre[c+1]; s2 += pre[c+2]; s3 += pre[c+3]; }
        const float mu = ((s0 + s1) + (s2 + s3)) * (1.f / 32.f);
        float v0 = 0.f, v1 = 0.f, v2 = 0.f, v3 = 0.f;
#pragma unroll
        for (int c = 0; c < 32; c += 4) {
            pre[c]   -= mu; v0 = fmaf(pre[c],   pre[c],   v0);
            pre[c+1] -= mu; v1 = fmaf(pre[c+1], pre[c+1], v1);
            pre[c+2] -= mu; v2 = fmaf(pre[c+2], pre[c+2], v2);
            pre[c+3] -= mu; v3 = fmaf(pre[c+3], pre[c+3], v3);
        }
        const float rstd = rsqrtf(fmaf((v0 + v1) + (v2 + v3), 1.f / 32.f, 1e-5f));
#pragma unroll
        for (int c = 0; c < 32; ++c)
            pre[c] = fmaxf(fmaf(pre[c] * rstd, ln_g[c], ln_b[c]), 0.f);
#pragma unroll
        for (int q = 0; q < 16; ++q) {
            uint rr;
            asm("v_cvt_pk_bf16_f32 %0, %1, %2" : "=v"(rr) : "v"(pre[2*q]), "v"(pre[2*q+1]));
            hw[q] = rr;
        }
    };
    auto write_h = [&]() {
        uint* hrow = &h_lds[j * 17];
        *reinterpret_cast<uint4*>(hrow + 0)  = make_uint4(hw[0],  hw[1],  hw[2],  hw[3]);
        *reinterpret_cast<uint4*>(hrow + 4)  = make_uint4(hw[4],  hw[5],  hw[6],  hw[7]);
        *reinterpret_cast<uint4*>(hrow + 8)  = make_uint4(hw[8],  hw[9],  hw[10], hw[11]);
        *reinterpret_cast<uint4*>(hrow + 12) = make_uint4(hw[12], hw[13], hw[14], hw[15]);
    };
    auto mfma_row = [&](int r) {
        const int row = row0 + r;
        const float scale = visited[row] ? 0.5f : 1.0f;   // uniform
        v4f accsum = {0.f, 0.f, 0.f, 0.f};
#pragma unroll
        for (int t = 0; t < 4; ++t) {
            const int edge = wv * 64 + t * 16 + eRow;
            const bf16x8 bfr = *reinterpret_cast<const bf16x8*>(&h_lds[edge * 17 + g * 4]);
            v4f acc = {ub2v.x, ub2v.y, ub2v.z, ub2v.w};
            acc = __builtin_amdgcn_mfma_f32_16x16x32_bf16(alo, bfr, acc, 0, 0, 0);
            acc = __builtin_amdgcn_mfma_f32_16x16x32_bf16(ahi, bfr, acc, 0, 0, 0);
            acc[0] *= scale; acc[1] *= scale; acc[2] *= scale; acc[3] *= scale;
            *reinterpret_cast<v4f*>(ef_out + ((size_t)row * NN + edge) * 16 + g * 4) = acc;
            accsum += acc;
        }
#pragma unroll
        for (int rr = 0; rr < 4; ++rr) {
            float v = accsum[rr];
            v += __shfl_xor(v, 1);
            v += __shfl_xor(v, 2);
            v += __shfl_xor(v, 4);
            v += __shfl_xor(v, 8);
            accsum[rr] = v;
        }
        if (eRow == 0)
            *reinterpret_cast<v4f*>(&red2[r][wv][g * 4]) = accsum;
    };

    // ---- pipelined 4-row loop --------------------------------------------------
    compute_h(0);
    write_h();
#pragma unroll
    for (int r = 0; r < 3; ++r) {
        compute_h(r + 1);   // VALU: fills the write->read DS gap of row r
        mfma_row(r);        // ds_read + MFMA + stores (stores drain under next iter)
        write_h();          // in-order DS: safe after mfma_row's reads
    }
    mfma_row(3);

    __syncthreads();   // red2 complete for all rows

    // pooled means
    if (j < 64) {
        const int r = j >> 4, e = j & 15;
        pool_s[r][e] = (red2[r][0][e] + red2[r][1][e] + red2[r][2][e] + red2[r][3][e])
                       * (1.f / 256.f);
    }
    __syncthreads();

    // node MLP layer 1
    {
        const int r = j >> 6, u = j & 63;
        float s = nb1[u];
#pragma unroll
        for (int e = 0; e < 16; ++e)
            s = fmaf(pool_s[r][e], nW1[e * 64 + u], s);
        hid_s[r][u] = fmaxf(s, 0.f);
    }
    __syncthreads();

    // node MLP layer 2 (4x128 = 512 outputs, 2 passes)
#pragma unroll
    for (int p = 0; p < 2; ++p) {
        const int idx = p * 256 + j;
        const int r = idx >> 7, o = idx & 127;
        float s = nb2[o];
#pragma unroll 8
        for (int q = 0; q < 64; ++q)
            s = fmaf(hid_s[r][q], nW2[q * 128 + o], s);
        msg_out[(size_t)(row0 + r) * 128 + o] = s;
    }
}

extern "C" void kernel_launch(void* const* d_in, const int* in_sizes, int n_in,
                              void* d_out, int out_size, void* d_ws, size_t ws_size,
                              hipStream_t stream)
{
    const float* node    = (const float*)d_in[0];
    const float* dist    = (const float*)d_in[1];
    const int*   visited = (const int*)  d_in[2];
    const float* dW1     = (const float*)d_in[3];
    const float* db1     = (const float*)d_in[4];
    const float* dW2     = (const float*)d_in[5];
    const float* db2     = (const float*)d_in[6];
    const float* uW1     = (const float*)d_in[7];
    const float* ub1     = (const float*)d_in[8];
    const float* ln_g    = (const float*)d_in[9];
    const float* ln_b    = (const float*)d_in[10];
    const float* uW2     = (const float*)d_in[11];
    const float* ub2     = (const float*)d_in[12];
    const float* nW1     = (const float*)d_in[13];
    const float* nb1     = (const float*)d_in[14];
    const float* nW2     = (const float*)d_in[15];
    const float* nb2     = (const float*)d_in[16];

    float* ws   = (float*)d_ws;
    float* bps  = ws;                    // 16
    float* albe = ws + 16;               // 1280 (1156 used + pad)
    float* Pi   = ws + 16 + 1280;        // 4096*32
    float* Pj   = Pi + 4096 * 32;        // 4096*32

    float* out = (float*)d_out;
    float* msg = out + EF_ELEMS;

    hipLaunchKernelGGL(k_prep_proj, dim3(1025), dim3(256), 0, stream,
                       node, uW1, dW1, db1, dW2, db2, ub1, bps, albe, Pi, Pj);
    hipLaunchKernelGGL(k_edge6, dim3(1024), dim3(256), 0, stream,
                       dist, visited, ln_g, ln_b, uW2, ub2, bps, albe, Pi, Pj,
                       nW1, nb1, nW2, nb2, out, msg);
}